// Round 5
// baseline (205.420 us; speedup 1.0000x reference)
//
#include <hip/hip_runtime.h>
#include <math.h>

typedef __attribute__((ext_vector_type(8))) short bf16x8;
typedef __attribute__((ext_vector_type(4))) float f32x4;
typedef unsigned long long ull;

__device__ __forceinline__ float sigmoidf_(float x) { return 1.f / (1.f + expf(-x)); }

__device__ __forceinline__ unsigned short f2bf(float f) {
  unsigned int u = __float_as_uint(f);
  u += 0x7fffu + ((u >> 16) & 1u);   // round-to-nearest-even
  return (unsigned short)(u >> 16);
}
__device__ __forceinline__ float bf2f(unsigned short u) {
  return __uint_as_float(((unsigned int)u) << 16);
}

// ws layout (float offsets)
#define WS_BEFF  0       // 64
#define WS_SEFF  64      // 64
#define WS_WFRAG 128     // 12288 ushort = 6144 floats

// ================= kCtl: full controller, one block per group (4 x 1024) =================
// Phases h/gates/LN/heads/tau computed redundantly per block (tiny); then
// group-specific attention scores + softmax + top3 + blend + wfrag pack.
__global__ __launch_bounds__(1024) void kCtl(
    const float* __restrict__ grads, const float* __restrict__ ctrl_w, const float* __restrict__ ctrl_b,
    const float* __restrict__ gp_w, const float* __restrict__ gp_b,
    const float* __restrict__ gt_w, const float* __restrict__ gt_b,
    const float* __restrict__ ln_g, const float* __restrict__ ln_b,
    const float* __restrict__ ccin_w, const float* __restrict__ ccin_b,
    const float* __restrict__ ck_w, const float* __restrict__ ck_b,
    const float* __restrict__ cb_w, const float* __restrict__ cb_b,
    const float* __restrict__ cf_w, const float* __restrict__ cf_b,
    const float* __restrict__ tau_w, const float* __restrict__ tau_b,
    const float* __restrict__ q_ema, const float* __restrict__ mem_W,
    const float* __restrict__ temp_logit,
    const float* __restrict__ conv_weight, const float* __restrict__ bias,
    float* __restrict__ ws) {
  __shared__ float rawA[8514];
  __shared__ float sh_h[64 * 65];
  __shared__ float gnp[64 * 17];
  __shared__ float taup[64];
  __shared__ float sh_qg[4416];      // grouped [g][1104]
  __shared__ float part[16][32];
  __shared__ float sv[3];
  __shared__ int sidx[3];
  __shared__ float qc1[16][64];
  __shared__ float qk1[16][3];
  __shared__ float sh_tau;
  const int tid = threadIdx.x;
  const int g = blockIdx.x;
  const int j = tid & 63;
  const int wv = tid >> 6;           // 0..15
  const int i0 = wv * 4;
  const int i0u = __builtin_amdgcn_readfirstlane(i0);

  // ---- h = silu(g @ ctrl_w.T + ctrl_b), K=192 in two halves ----
  float acc[4] = {0.f, 0.f, 0.f, 0.f};
  for (int hh = 0; hh < 2; ++hh) {
    const int d0 = hh * 96;
    for (int t = tid; t < 6144; t += 1024) {
      int jj = t / 96, dl = t - jj * 96;
      rawA[dl * 66 + jj] = ctrl_w[jj * 192 + d0 + dl];
    }
    __syncthreads();
    const float* g0 = grads + i0u * 192 + d0;
#pragma unroll 8
    for (int dl = 0; dl < 96; ++dl) {
      float wvv = rawA[dl * 66 + j];
      acc[0] += wvv * g0[dl];
      acc[1] += wvv * g0[192 + dl];
      acc[2] += wvv * g0[384 + dl];
      acc[3] += wvv * g0[576 + dl];
    }
    __syncthreads();
  }
  {
    float cb_ = ctrl_b[j];
#pragma unroll
    for (int ii = 0; ii < 4; ++ii) {
      float s = acc[ii] + cb_;
      sh_h[(i0 + ii) * 65 + j] = s * sigmoidf_(s);
    }
  }
  // ---- gn partials ----
  {
    int gi = tid >> 4, seg = tid & 15;
    const float* gr = grads + gi * 192 + seg * 12;
    float ss = 0.f;
#pragma unroll
    for (int m = 0; m < 12; ++m) { float v = gr[m]; ss += v * v; }
    gnp[gi * 17 + seg] = ss;
  }
  __syncthreads();
  if (tid < 64) {
    float s = 0.f;
#pragma unroll
    for (int seg = 0; seg < 16; ++seg) s += gnp[tid * 17 + seg];
    gnp[tid * 17 + 16] = sqrtf(s);
  }
  for (int t = tid; t < 4096; t += 1024) rawA[(t & 63) * 66 + (t >> 6)] = gt_w[t];
  for (int t = tid; t < 4160; t += 1024) {
    int jj = t / 65, dd = t - jj * 65;
    rawA[4224 + dd * 66 + jj] = gp_w[t];
  }
  __syncthreads();

  // ---- gates -> hm ----
  float hm[4];
  {
    float zacc[4] = {0.f, 0.f, 0.f, 0.f}, tacc[4] = {0.f, 0.f, 0.f, 0.f};
#pragma unroll 4
    for (int d = 0; d < 64; ++d) {
      float gtv = rawA[d * 66 + j];
      float gpv = rawA[4224 + d * 66 + j];
#pragma unroll
      for (int ii = 0; ii < 4; ++ii) {
        float hv = sh_h[(i0 + ii) * 65 + d];
        tacc[ii] += hv * gtv;
        zacc[ii] += hv * gpv;
      }
    }
    float gplast = rawA[4224 + 64 * 66 + j];
    float zb = gp_b[j], tb = gt_b[j];
#pragma unroll
    for (int ii = 0; ii < 4; ++ii) {
      float gn_ = gnp[(i0 + ii) * 17 + 16];
      float zs = zacc[ii] + gn_ * gplast + zb;
      float ts = tacc[ii] + tb;
      float z = sigmoidf_(zs);
      float ht = ts * sigmoidf_(ts);
      hm[ii] = (1.f - z) * sh_h[(i0 + ii) * 65 + j] + z * ht;
    }
  }
  __syncthreads();
#pragma unroll
  for (int ii = 0; ii < 4; ++ii) sh_h[(i0 + ii) * 65 + j] = hm[ii];
  __syncthreads();

  // ---- LN + stage ccinT/ext ----
  {
    float lg = ln_g[j], lb = ln_b[j];
#pragma unroll
    for (int ii = 0; ii < 4; ++ii) {
      float x = sh_h[(i0 + ii) * 65 + j];
      float s = x;
#pragma unroll
      for (int off = 32; off; off >>= 1) s += __shfl_xor(s, off);
      float mu = s * (1.f / 64.f);
      float dv = x - mu;
      float v2 = dv * dv;
#pragma unroll
      for (int off = 32; off; off >>= 1) v2 += __shfl_xor(v2, off);
      float invs = 1.f / sqrtf(v2 * (1.f / 64.f) + 1e-5f);
      sh_h[(i0 + ii) * 65 + j] = lg * dv * invs + lb;
    }
  }
  for (int t = tid; t < 4096; t += 1024) rawA[(t & 63) * 66 + (t >> 6)] = ccin_w[t];
  if (tid < 384) {
    int c = tid >> 6, d = tid & 63;
    float v = (c < 3) ? ck_w[c * 64 + d] : (c == 3) ? cb_w[d] : (c == 4) ? cf_w[d] : tau_w[d];
    rawA[4224 + c * 64 + d] = v;
  }
  __syncthreads();

  // ---- w_cin head (all rows) ----
  {
    float cb_ = ccin_b[j];
    float s4[4] = {0.f, 0.f, 0.f, 0.f};
#pragma unroll 4
    for (int d = 0; d < 64; ++d) {
      float cv = rawA[d * 66 + j];
#pragma unroll
      for (int ii = 0; ii < 4; ++ii) s4[ii] += sh_h[(i0 + ii) * 65 + d] * cv;
    }
#pragma unroll
    for (int ii = 0; ii < 4; ++ii) {
      int i = i0 + ii;
      float val = 2.f * tanhf(s4[ii] + cb_);
      sh_qg[(i >> 4) * 1104 + (i & 15) * 64 + j] = 0.7f * val + 0.3f * q_ema[i * 64 + j];
    }
  }
  // ---- extras: ck(3), cb, cf, tau ----
  if (wv < 6) {
    int i = j;
    float s = 0.f;
    const float* er = rawA + 4224 + wv * 64;
#pragma unroll 4
    for (int d = 0; d < 64; ++d) s += sh_h[i * 65 + d] * er[d];
    if (wv < 3) {
      float val = 2.f * tanhf(s + ck_b[wv]);
      sh_qg[(i >> 4) * 1104 + 1024 + (i & 15) * 3 + wv] = 0.7f * val + 0.3f * q_ema[4096 + i * 3 + wv];
    } else if (wv == 3) {
      float val = 2.f * tanhf(s + cb_b[0]);
      sh_qg[(i >> 4) * 1104 + 1072 + (i & 15)] = 0.7f * val + 0.3f * q_ema[4288 + i];
    } else if (wv == 4) {
      float val = 2.f * tanhf(s + cf_b[0]);
      sh_qg[(i >> 4) * 1104 + 1088 + (i & 15)] = 0.7f * val + 0.3f * q_ema[4352 + i];
    } else {
      taup[i] = sigmoidf_(s + tau_b[0]);
    }
  }
  __syncthreads();
  if (tid < 64) {
    float t_ = taup[tid];
#pragma unroll
    for (int off = 32; off; off >>= 1) t_ += __shfl_xor(t_, off);
    if (tid == 0) sh_tau = (t_ * (1.f / 64.f)) * 0.5f + 0.5f;
  }
  __syncthreads();

  // ---- attention scores for this group: 1024 threads over (d-slice, m4) ----
  const float* mwg = mem_W + (size_t)g * 1104 * 32;
  {
    float4 a = {0.f, 0.f, 0.f, 0.f};
    const float* qg = sh_qg + g * 1104;
#pragma unroll
    for (int it = 0; it < 9; ++it) {
      int d = it * 128 + (tid >> 3);
      if (d < 1104) {
        float4 v4 = *(const float4*)(mwg + (size_t)d * 32 + (tid & 7) * 4);
        float qv = qg[d];
        a.x += qv * v4.x; a.y += qv * v4.y; a.z += qv * v4.z; a.w += qv * v4.w;
      }
    }
#pragma unroll
    for (int off = 8; off <= 32; off <<= 1) {
      a.x += __shfl_xor(a.x, off); a.y += __shfl_xor(a.y, off);
      a.z += __shfl_xor(a.z, off); a.w += __shfl_xor(a.w, off);
    }
    if ((tid & 63) < 8) *(float4*)&part[tid >> 6][(tid & 7) * 4] = a;
  }
  __syncthreads();

  // ---- softmax + top3 ----
  if (tid < 32) {
    int m = tid;
    float att = 0.f;
#pragma unroll
    for (int w = 0; w < 16; ++w) att += part[w][m];
    float temp = 0.6f * sigmoidf_(temp_logit[g]) + 0.2f;
    att /= (temp + 1e-8f);
    float mx = att;
#pragma unroll
    for (int off = 16; off; off >>= 1) mx = fmaxf(mx, __shfl_xor(mx, off, 32));
    float e = expf(att - mx);
    float s = e;
#pragma unroll
    for (int off = 16; off; off >>= 1) s += __shfl_xor(s, off, 32);
    float p = e / s;
    for (int t = 0; t < 3; ++t) {
      float bp = p; int bm = m;
#pragma unroll
      for (int off = 16; off; off >>= 1) {
        float op = __shfl_xor(bp, off, 32);
        int om = __shfl_xor(bm, off, 32);
        if (op > bp || (op == bp && om < bm)) { bp = op; bm = om; }
      }
      if (m == 0) { sv[t] = bp; sidx[t] = bm; }
      if (m == bm) p = -1.f;
    }
  }
  __syncthreads();

  // ---- q-final blend for this group's 16 co ----
  {
    const float tau = sh_tau;
    const float v0 = sv[0], v1 = sv[1], v2 = sv[2];
    const int x0 = sidx[0], x1 = sidx[1], x2 = sidx[2];
    const float* qg = sh_qg + g * 1104;
    int cl = wv;           // 0..15
    int co = 16 * g + cl;
    int lane = j;
    {
      int d = cl * 64 + lane;
      float r = v0 * mwg[(size_t)d * 32 + x0] + v1 * mwg[(size_t)d * 32 + x1] + v2 * mwg[(size_t)d * 32 + x2];
      qc1[cl][lane] = 1.f + tau * qg[d] + (1.f - tau) * r;
    }
    if (lane < 3) {
      int d = 1024 + cl * 3 + lane;
      float r = v0 * mwg[(size_t)d * 32 + x0] + v1 * mwg[(size_t)d * 32 + x1] + v2 * mwg[(size_t)d * 32 + x2];
      qk1[cl][lane] = 1.f + tau * qg[d] + (1.f - tau) * r;
    }
    if (lane == 3) {
      int d = 1072 + cl;
      float r = v0 * mwg[(size_t)d * 32 + x0] + v1 * mwg[(size_t)d * 32 + x1] + v2 * mwg[(size_t)d * 32 + x2];
      float qb = tau * qg[d] + (1.f - tau) * r;
      ws[WS_BEFF + co] = bias[co] * (1.f + qb);
    }
    if (lane == 4) {
      int d = 1088 + cl;
      float r = v0 * mwg[(size_t)d * 32 + x0] + v1 * mwg[(size_t)d * 32 + x1] + v2 * mwg[(size_t)d * 32 + x2];
      ws[WS_SEFF + co] = 1.f + tau * qg[d] + (1.f - tau) * r;
    }
  }
  __syncthreads();

  // ---- pack wfrag for this group's 16 co (3072 entries) ----
  unsigned short* wfrag = (unsigned short*)(ws + WS_WFRAG);
  for (int idx = tid; idx < 3072; idx += 1024) {
    int cl = idx / 192, rem = idx - cl * 192;
    int kk = rem >> 6, ci = rem & 63;
    int co = 16 * g + cl;
    float val = conv_weight[(co * 64 + ci) * 3 + kk] * qc1[cl][ci] * qk1[cl][kk];
    int e = kk * 64 + ci;
    int s = e >> 5, hi = (e >> 3) & 3, jj = e & 7;
    wfrag[s * 2048 + g * 512 + (16 * hi + cl) * 8 + jj] = f2bf(val);
  }
}

// ================= k3_y: conv1d via MFMA, y-decomposition, swizzled LDS =================
// grid (32 l-tiles of 256, 64 batches), 256 threads = 4 waves.
// LDS xs[pos][cp] u32 (cp = ci pair), row 128 B, swizzle byte ^= (pos&15)<<3.
// Reads: 2x ds_read_b64 per K-half, conflict-free. Writes: u32, 2 lanes/bank.
__global__ __launch_bounds__(256, 4) void k3_y(
    const float* __restrict__ x, const unsigned short* __restrict__ wfrag,
    const float* __restrict__ beff, const float* __restrict__ seff,
    float* __restrict__ out) {
  __shared__ unsigned short xs[256 * 64];   // 32 KB
  __shared__ float lhal[64], rhal[64];
  const int tid = threadIdx.x;
  const int w = tid >> 6, l = tid & 63;
  const int g = l >> 4, c16 = l & 15;
  const int n = blockIdx.y;
  const int l0 = blockIdx.x * 256;

  // B fragments: wf[2*kk + half]
  bf16x8 wf[6];
#pragma unroll
  for (int s = 0; s < 6; ++s)
    wf[s] = *(const bf16x8*)(wfrag + s * 2048 + w * 512 + l * 8);

  // halo columns
  if (tid < 64) {
    const float* rowp = x + ((size_t)(n * 64 + tid)) * 8192;
    lhal[tid] = (l0 > 0) ? rowp[l0 - 1] : 0.f;
    rhal[tid] = (l0 + 256 < 8192) ? rowp[l0 + 256] : 0.f;
  }

  // center staging: cp = 8w + (l>>3); pos = 4*((l&7)+8t)+i
  {
    const int cp = 8 * w + (l >> 3);
    const float* r0 = x + ((size_t)(n * 64 + 2 * cp)) * 8192 + l0;
    const float* r1 = r0 + 8192;
    char* xb = (char*)xs;
#pragma unroll
    for (int t = 0; t < 8; ++t) {
      int p0 = 4 * ((l & 7) + 8 * t);
      float4 va = *(const float4*)(r0 + p0);
      float4 vb = *(const float4*)(r1 + p0);
      float av[4] = {va.x, va.y, va.z, va.w};
      float bv[4] = {vb.x, vb.y, vb.z, vb.w};
#pragma unroll
      for (int i = 0; i < 4; ++i) {
        int pos = p0 + i;
        unsigned u = (unsigned)f2bf(av[i]) | ((unsigned)f2bf(bv[i]) << 16);
        *(unsigned*)(xb + pos * 128 + ((4 * cp) ^ ((pos & 15) << 3))) = u;
      }
    }
  }
  __syncthreads();

  // halo dots: y0 at pos l0-1, y2 at pos l0+256
  float s0 = 0.f, s2s = 0.f;
#pragma unroll
  for (int s = 0; s < 2; ++s) {
#pragma unroll
    for (int jj = 0; jj < 8; ++jj) {
      int ci = 32 * s + 8 * g + jj;
      s0  += bf2f((unsigned short)wf[s][jj]) * lhal[ci];
      s2s += bf2f((unsigned short)wf[4 + s][jj]) * rhal[ci];
    }
  }
  s0 += __shfl_xor(s0, 16);  s0 += __shfl_xor(s0, 32);
  s2s += __shfl_xor(s2s, 16); s2s += __shfl_xor(s2s, 32);
  float carry0 = s0;

  f32x4 o[16];
#pragma unroll
  for (int nt = 0; nt < 16; ++nt) o[nt] = (f32x4){0.f, 0.f, 0.f, 0.f};

  const char* xbc = (const char*)xs;
  const int sw = c16 << 3;            // (rp&15)<<3 with rp = 16nt + c16
#pragma unroll
  for (int nt = 0; nt < 16; ++nt) {
    const int rbase = (16 * nt + c16) * 128;
    union { bf16x8 v; ull d[2]; } A0, A1;
    A0.d[0] = *(const ull*)(xbc + rbase + ((16 * g) ^ sw));
    A0.d[1] = *(const ull*)(xbc + rbase + ((16 * g + 8) ^ sw));
    A1.d[0] = *(const ull*)(xbc + rbase + ((64 + 16 * g) ^ sw));
    A1.d[1] = *(const ull*)(xbc + rbase + ((64 + 16 * g + 8) ^ sw));
    o[nt] = __builtin_amdgcn_mfma_f32_16x16x32_bf16(A0.v, wf[2], o[nt], 0, 0, 0);
    o[nt] = __builtin_amdgcn_mfma_f32_16x16x32_bf16(A1.v, wf[3], o[nt], 0, 0, 0);
    f32x4 y0 = (f32x4){0.f, 0.f, 0.f, 0.f};
    f32x4 y2 = (f32x4){0.f, 0.f, 0.f, 0.f};
    y0 = __builtin_amdgcn_mfma_f32_16x16x32_bf16(A0.v, wf[0], y0, 0, 0, 0);
    y0 = __builtin_amdgcn_mfma_f32_16x16x32_bf16(A1.v, wf[1], y0, 0, 0, 0);
    y2 = __builtin_amdgcn_mfma_f32_16x16x32_bf16(A0.v, wf[4], y2, 0, 0, 0);
    y2 = __builtin_amdgcn_mfma_f32_16x16x32_bf16(A1.v, wf[5], y2, 0, 0, 0);
    // out[p] += y0[p-1]
    float sh = __shfl(y0[3], (l - 16) & 63);
    o[nt][0] += (g == 0) ? carry0 : sh;
    o[nt][1] += y0[0];
    o[nt][2] += y0[1];
    o[nt][3] += y0[2];
    carry0 = sh;
    // out[p] += y2[p+1]
    float b0 = __shfl(y2[0], (l + 16) & 63);
    o[nt][0] += y2[1];
    o[nt][1] += y2[2];
    o[nt][2] += y2[3];
    o[nt][3] += (g < 3) ? b0 : 0.f;
    if (nt > 0) o[nt - 1][3] += (g == 3) ? b0 : 0.f;
  }
  o[15][3] += (g == 3) ? s2s : 0.f;

  // epilogue: co = 16w + c16; pos = l0 + nt*16 + 4g + r
  const int co = 16 * w + c16;
  const float be = beff[co], se = seff[co];
  float* orow = out + ((size_t)(n * 64 + co)) * 8192 + l0 + 4 * g;
#pragma unroll
  for (int nt = 0; nt < 16; ++nt) {
    float4 ov;
    ov.x = se * (o[nt][0] + be);
    ov.y = se * (o[nt][1] + be);
    ov.z = se * (o[nt][2] + be);
    ov.w = se * (o[nt][3] + be);
    *(float4*)(orow + nt * 16) = ov;
  }
}

extern "C" void kernel_launch(void* const* d_in, const int* in_sizes, int n_in,
                              void* d_out, int out_size, void* d_ws, size_t ws_size,
                              hipStream_t stream) {
  const float* x = (const float*)d_in[0];
  const float* conv_weight = (const float*)d_in[1];
  const float* bias = (const float*)d_in[2];
  const float* grads = (const float*)d_in[3];
  const float* q_ema = (const float*)d_in[4];
  const float* ctrl_w = (const float*)d_in[5];
  const float* ctrl_b = (const float*)d_in[6];
  const float* gp_w = (const float*)d_in[7];
  const float* gp_b = (const float*)d_in[8];
  const float* gt_w = (const float*)d_in[9];
  const float* gt_b = (const float*)d_in[10];
  const float* ln_g = (const float*)d_in[11];
  const float* ln_b = (const float*)d_in[12];
  const float* ccin_w = (const float*)d_in[13];
  const float* ccin_b = (const float*)d_in[14];
  const float* ck_w = (const float*)d_in[15];
  const float* ck_b = (const float*)d_in[16];
  const float* cb_w = (const float*)d_in[17];
  const float* cb_b = (const float*)d_in[18];
  const float* cf_w = (const float*)d_in[19];
  const float* cf_b = (const float*)d_in[20];
  const float* tau_w = (const float*)d_in[21];
  const float* tau_b = (const float*)d_in[22];
  const float* mem_W = (const float*)d_in[23];
  const float* temp_logit = (const float*)d_in[24];

  float* ws = (float*)d_ws;

  hipLaunchKernelGGL(kCtl, dim3(4), dim3(1024), 0, stream,
                     grads, ctrl_w, ctrl_b, gp_w, gp_b, gt_w, gt_b, ln_g, ln_b,
                     ccin_w, ccin_b, ck_w, ck_b, cb_w, cb_b, cf_w, cf_b,
                     tau_w, tau_b, q_ema, mem_W, temp_logit, conv_weight, bias, ws);
  hipLaunchKernelGGL(k3_y, dim3(32, 64), dim3(256), 0, stream,
                     x, (const unsigned short*)(ws + WS_WFRAG), ws + WS_BEFF, ws + WS_SEFF,
                     (float*)d_out);
}

// Round 6
// 102.518 us; speedup vs baseline: 2.0037x; 2.0037x over previous
//
#include <hip/hip_runtime.h>
#include <math.h>

typedef __attribute__((ext_vector_type(8))) short bf16x8;
typedef __attribute__((ext_vector_type(4))) float f32x4;
typedef unsigned long long ull;

__device__ __forceinline__ float sigmoidf_(float x) { return 1.f / (1.f + expf(-x)); }

__device__ __forceinline__ unsigned short f2bf(float f) {
  unsigned int u = __float_as_uint(f);
  u += 0x7fffu + ((u >> 16) & 1u);   // round-to-nearest-even
  return (unsigned short)(u >> 16);
}

// ws layout (float offsets)
#define WS_BEFF  0       // 64
#define WS_SEFF  64      // 64
#define WS_WFRAG 128     // 12288 ushort = 6144 floats

// ================= kCtl: full controller, one block per group (4 x 1024) =================
__global__ __launch_bounds__(1024) void kCtl(
    const float* __restrict__ grads, const float* __restrict__ ctrl_w, const float* __restrict__ ctrl_b,
    const float* __restrict__ gp_w, const float* __restrict__ gp_b,
    const float* __restrict__ gt_w, const float* __restrict__ gt_b,
    const float* __restrict__ ln_g, const float* __restrict__ ln_b,
    const float* __restrict__ ccin_w, const float* __restrict__ ccin_b,
    const float* __restrict__ ck_w, const float* __restrict__ ck_b,
    const float* __restrict__ cb_w, const float* __restrict__ cb_b,
    const float* __restrict__ cf_w, const float* __restrict__ cf_b,
    const float* __restrict__ tau_w, const float* __restrict__ tau_b,
    const float* __restrict__ q_ema, const float* __restrict__ mem_W,
    const float* __restrict__ temp_logit,
    const float* __restrict__ conv_weight, const float* __restrict__ bias,
    float* __restrict__ ws) {
  __shared__ float rawA[8514];
  __shared__ float sh_h[64 * 65];
  __shared__ float gnp[64 * 17];
  __shared__ float taup[64];
  __shared__ float sh_qg[4416];      // grouped [g][1104]
  __shared__ float part[16][32];
  __shared__ float sv[3];
  __shared__ int sidx[3];
  __shared__ float qc1[16][64];
  __shared__ float qk1[16][3];
  __shared__ float sh_tau;
  const int tid = threadIdx.x;
  const int g = blockIdx.x;
  const int j = tid & 63;
  const int wv = tid >> 6;           // 0..15
  const int i0 = wv * 4;
  const int i0u = __builtin_amdgcn_readfirstlane(i0);

  // ---- h = silu(g @ ctrl_w.T + ctrl_b), K=192 in two halves ----
  float acc[4] = {0.f, 0.f, 0.f, 0.f};
  for (int hh = 0; hh < 2; ++hh) {
    const int d0 = hh * 96;
    for (int t = tid; t < 6144; t += 1024) {
      int jj = t / 96, dl = t - jj * 96;
      rawA[dl * 66 + jj] = ctrl_w[jj * 192 + d0 + dl];
    }
    __syncthreads();
    const float* g0 = grads + i0u * 192 + d0;
#pragma unroll 8
    for (int dl = 0; dl < 96; ++dl) {
      float wvv = rawA[dl * 66 + j];
      acc[0] += wvv * g0[dl];
      acc[1] += wvv * g0[192 + dl];
      acc[2] += wvv * g0[384 + dl];
      acc[3] += wvv * g0[576 + dl];
    }
    __syncthreads();
  }
  {
    float cb_ = ctrl_b[j];
#pragma unroll
    for (int ii = 0; ii < 4; ++ii) {
      float s = acc[ii] + cb_;
      sh_h[(i0 + ii) * 65 + j] = s * sigmoidf_(s);
    }
  }
  // ---- gn partials ----
  {
    int gi = tid >> 4, seg = tid & 15;
    const float* gr = grads + gi * 192 + seg * 12;
    float ss = 0.f;
#pragma unroll
    for (int m = 0; m < 12; ++m) { float v = gr[m]; ss += v * v; }
    gnp[gi * 17 + seg] = ss;
  }
  __syncthreads();
  if (tid < 64) {
    float s = 0.f;
#pragma unroll
    for (int seg = 0; seg < 16; ++seg) s += gnp[tid * 17 + seg];
    gnp[tid * 17 + 16] = sqrtf(s);
  }
  for (int t = tid; t < 4096; t += 1024) rawA[(t & 63) * 66 + (t >> 6)] = gt_w[t];
  for (int t = tid; t < 4160; t += 1024) {
    int jj = t / 65, dd = t - jj * 65;
    rawA[4224 + dd * 66 + jj] = gp_w[t];
  }
  __syncthreads();

  // ---- gates -> hm ----
  float hm[4];
  {
    float zacc[4] = {0.f, 0.f, 0.f, 0.f}, tacc[4] = {0.f, 0.f, 0.f, 0.f};
#pragma unroll 4
    for (int d = 0; d < 64; ++d) {
      float gtv = rawA[d * 66 + j];
      float gpv = rawA[4224 + d * 66 + j];
#pragma unroll
      for (int ii = 0; ii < 4; ++ii) {
        float hv = sh_h[(i0 + ii) * 65 + d];
        tacc[ii] += hv * gtv;
        zacc[ii] += hv * gpv;
      }
    }
    float gplast = rawA[4224 + 64 * 66 + j];
    float zb = gp_b[j], tb = gt_b[j];
#pragma unroll
    for (int ii = 0; ii < 4; ++ii) {
      float gn_ = gnp[(i0 + ii) * 17 + 16];
      float zs = zacc[ii] + gn_ * gplast + zb;
      float ts = tacc[ii] + tb;
      float z = sigmoidf_(zs);
      float ht = ts * sigmoidf_(ts);
      hm[ii] = (1.f - z) * sh_h[(i0 + ii) * 65 + j] + z * ht;
    }
  }
  __syncthreads();
#pragma unroll
  for (int ii = 0; ii < 4; ++ii) sh_h[(i0 + ii) * 65 + j] = hm[ii];
  __syncthreads();

  // ---- LN + stage ccinT/ext ----
  {
    float lg = ln_g[j], lb = ln_b[j];
#pragma unroll
    for (int ii = 0; ii < 4; ++ii) {
      float x = sh_h[(i0 + ii) * 65 + j];
      float s = x;
#pragma unroll
      for (int off = 32; off; off >>= 1) s += __shfl_xor(s, off);
      float mu = s * (1.f / 64.f);
      float dv = x - mu;
      float v2 = dv * dv;
#pragma unroll
      for (int off = 32; off; off >>= 1) v2 += __shfl_xor(v2, off);
      float invs = 1.f / sqrtf(v2 * (1.f / 64.f) + 1e-5f);
      sh_h[(i0 + ii) * 65 + j] = lg * dv * invs + lb;
    }
  }
  for (int t = tid; t < 4096; t += 1024) rawA[(t & 63) * 66 + (t >> 6)] = ccin_w[t];
  if (tid < 384) {
    int c = tid >> 6, d = tid & 63;
    float v = (c < 3) ? ck_w[c * 64 + d] : (c == 3) ? cb_w[d] : (c == 4) ? cf_w[d] : tau_w[d];
    rawA[4224 + c * 64 + d] = v;
  }
  __syncthreads();

  // ---- w_cin head (all rows) ----
  {
    float cb_ = ccin_b[j];
    float s4[4] = {0.f, 0.f, 0.f, 0.f};
#pragma unroll 4
    for (int d = 0; d < 64; ++d) {
      float cv = rawA[d * 66 + j];
#pragma unroll
      for (int ii = 0; ii < 4; ++ii) s4[ii] += sh_h[(i0 + ii) * 65 + d] * cv;
    }
#pragma unroll
    for (int ii = 0; ii < 4; ++ii) {
      int i = i0 + ii;
      float val = 2.f * tanhf(s4[ii] + cb_);
      sh_qg[(i >> 4) * 1104 + (i & 15) * 64 + j] = 0.7f * val + 0.3f * q_ema[i * 64 + j];
    }
  }
  // ---- extras: ck(3), cb, cf, tau ----
  if (wv < 6) {
    int i = j;
    float s = 0.f;
    const float* er = rawA + 4224 + wv * 64;
#pragma unroll 4
    for (int d = 0; d < 64; ++d) s += sh_h[i * 65 + d] * er[d];
    if (wv < 3) {
      float val = 2.f * tanhf(s + ck_b[wv]);
      sh_qg[(i >> 4) * 1104 + 1024 + (i & 15) * 3 + wv] = 0.7f * val + 0.3f * q_ema[4096 + i * 3 + wv];
    } else if (wv == 3) {
      float val = 2.f * tanhf(s + cb_b[0]);
      sh_qg[(i >> 4) * 1104 + 1072 + (i & 15)] = 0.7f * val + 0.3f * q_ema[4288 + i];
    } else if (wv == 4) {
      float val = 2.f * tanhf(s + cf_b[0]);
      sh_qg[(i >> 4) * 1104 + 1088 + (i & 15)] = 0.7f * val + 0.3f * q_ema[4352 + i];
    } else {
      taup[i] = sigmoidf_(s + tau_b[0]);
    }
  }
  __syncthreads();
  if (tid < 64) {
    float t_ = taup[tid];
#pragma unroll
    for (int off = 32; off; off >>= 1) t_ += __shfl_xor(t_, off);
    if (tid == 0) sh_tau = (t_ * (1.f / 64.f)) * 0.5f + 0.5f;
  }
  __syncthreads();

  // ---- attention scores for this group ----
  const float* mwg = mem_W + (size_t)g * 1104 * 32;
  {
    float4 a = {0.f, 0.f, 0.f, 0.f};
    const float* qg = sh_qg + g * 1104;
#pragma unroll
    for (int it = 0; it < 9; ++it) {
      int d = it * 128 + (tid >> 3);
      if (d < 1104) {
        float4 v4 = *(const float4*)(mwg + (size_t)d * 32 + (tid & 7) * 4);
        float qv = qg[d];
        a.x += qv * v4.x; a.y += qv * v4.y; a.z += qv * v4.z; a.w += qv * v4.w;
      }
    }
#pragma unroll
    for (int off = 8; off <= 32; off <<= 1) {
      a.x += __shfl_xor(a.x, off); a.y += __shfl_xor(a.y, off);
      a.z += __shfl_xor(a.z, off); a.w += __shfl_xor(a.w, off);
    }
    if ((tid & 63) < 8) *(float4*)&part[tid >> 6][(tid & 7) * 4] = a;
  }
  __syncthreads();

  // ---- softmax + top3 ----
  if (tid < 32) {
    int m = tid;
    float att = 0.f;
#pragma unroll
    for (int w = 0; w < 16; ++w) att += part[w][m];
    float temp = 0.6f * sigmoidf_(temp_logit[g]) + 0.2f;
    att /= (temp + 1e-8f);
    float mx = att;
#pragma unroll
    for (int off = 16; off; off >>= 1) mx = fmaxf(mx, __shfl_xor(mx, off, 32));
    float e = expf(att - mx);
    float s = e;
#pragma unroll
    for (int off = 16; off; off >>= 1) s += __shfl_xor(s, off, 32);
    float p = e / s;
    for (int t = 0; t < 3; ++t) {
      float bp = p; int bm = m;
#pragma unroll
      for (int off = 16; off; off >>= 1) {
        float op = __shfl_xor(bp, off, 32);
        int om = __shfl_xor(bm, off, 32);
        if (op > bp || (op == bp && om < bm)) { bp = op; bm = om; }
      }
      if (m == 0) { sv[t] = bp; sidx[t] = bm; }
      if (m == bm) p = -1.f;
    }
  }
  __syncthreads();

  // ---- q-final blend for this group's 16 co ----
  {
    const float tau = sh_tau;
    const float v0 = sv[0], v1 = sv[1], v2 = sv[2];
    const int x0 = sidx[0], x1 = sidx[1], x2 = sidx[2];
    const float* qg = sh_qg + g * 1104;
    int cl = wv;           // 0..15
    int co = 16 * g + cl;
    int lane = j;
    {
      int d = cl * 64 + lane;
      float r = v0 * mwg[(size_t)d * 32 + x0] + v1 * mwg[(size_t)d * 32 + x1] + v2 * mwg[(size_t)d * 32 + x2];
      qc1[cl][lane] = 1.f + tau * qg[d] + (1.f - tau) * r;
    }
    if (lane < 3) {
      int d = 1024 + cl * 3 + lane;
      float r = v0 * mwg[(size_t)d * 32 + x0] + v1 * mwg[(size_t)d * 32 + x1] + v2 * mwg[(size_t)d * 32 + x2];
      qk1[cl][lane] = 1.f + tau * qg[d] + (1.f - tau) * r;
    }
    if (lane == 3) {
      int d = 1072 + cl;
      float r = v0 * mwg[(size_t)d * 32 + x0] + v1 * mwg[(size_t)d * 32 + x1] + v2 * mwg[(size_t)d * 32 + x2];
      float qb = tau * qg[d] + (1.f - tau) * r;
      ws[WS_BEFF + co] = bias[co] * (1.f + qb);
    }
    if (lane == 4) {
      int d = 1088 + cl;
      float r = v0 * mwg[(size_t)d * 32 + x0] + v1 * mwg[(size_t)d * 32 + x1] + v2 * mwg[(size_t)d * 32 + x2];
      ws[WS_SEFF + co] = 1.f + tau * qg[d] + (1.f - tau) * r;
    }
  }
  __syncthreads();

  // ---- pack wfrag for this group's 16 co (3072 entries) ----
  unsigned short* wfrag = (unsigned short*)(ws + WS_WFRAG);
  for (int idx = tid; idx < 3072; idx += 1024) {
    int cl = idx / 192, rem = idx - cl * 192;
    int kk = rem >> 6, ci = rem & 63;
    int co = 16 * g + cl;
    float val = conv_weight[(co * 64 + ci) * 3 + kk] * qc1[cl][ci] * qk1[cl][kk];
    int e = kk * 64 + ci;
    int s = e >> 5, hi = (e >> 3) & 3, jj = e & 7;
    wfrag[s * 2048 + g * 512 + (16 * hi + cl) * 8 + jj] = f2bf(val);
  }
}

// ================= k3_s: round-3 direct MFMA conv, conflict-free swizzled LDS =================
// grid (32 l-tiles of 256, 64 batches), 256 threads = 4 waves.
// LDS row p (128 B, 32 u32 ci-pairs) ↔ global pos l0 + p - 1 (p = 0..257).
// swizzle: byte ^= (p&15)<<3. Writes: 2 lanes/bank (free). Reads: 2x b64, conflict-free.
__global__ __launch_bounds__(256, 4) void k3_s(
    const float* __restrict__ x, const unsigned short* __restrict__ wfrag,
    const float* __restrict__ beff, const float* __restrict__ seff,
    float* __restrict__ out) {
  __shared__ unsigned short xs[258 * 64];   // 33024 B
  const int tid = threadIdx.x;
  const int w = tid >> 6, l = tid & 63;
  const int g = l >> 4, c16 = l & 15;
  const int n = blockIdx.y;
  const int l0 = blockIdx.x * 256;

  // B fragments (round-3 layout)
  bf16x8 wf[6];
#pragma unroll
  for (int s = 0; s < 6; ++s)
    wf[s] = *(const bf16x8*)(wfrag + s * 2048 + w * 512 + l * 8);

  // staging: cp = ci-pair owned by this lane
  {
    const int cp = 8 * w + (l >> 3);
    const float* r0 = x + ((size_t)(n * 64 + 2 * cp)) * 8192 + l0;
    const float* r1 = r0 + 8192;
    char* xb = (char*)xs;
#pragma unroll
    for (int t = 0; t < 8; ++t) {
      int p0 = 4 * ((l & 7) + 8 * t);
      float4 va = *(const float4*)(r0 + p0);
      float4 vb = *(const float4*)(r1 + p0);
      float av[4] = {va.x, va.y, va.z, va.w};
      float bv[4] = {vb.x, vb.y, vb.z, vb.w};
#pragma unroll
      for (int i = 0; i < 4; ++i) {
        int p = p0 + i + 1;
        unsigned u = (unsigned)f2bf(av[i]) | ((unsigned)f2bf(bv[i]) << 16);
        *(unsigned*)(xb + p * 128 + ((4 * cp) ^ ((p & 15) << 3))) = u;
      }
    }
    // halo rows 0 (pos l0-1) and 257 (pos l0+256), handled by lanes with (l&7)==0
    if ((l & 7) == 0) {
      float a0 = 0.f, b0 = 0.f, a1 = 0.f, b1 = 0.f;
      if (l0 > 0) {
        float4 va = *(const float4*)(r0 - 4);
        float4 vb = *(const float4*)(r1 - 4);
        a0 = va.w; b0 = vb.w;
      }
      if (l0 + 256 < 8192) {
        float4 va = *(const float4*)(r0 + 256);
        float4 vb = *(const float4*)(r1 + 256);
        a1 = va.x; b1 = vb.x;
      }
      unsigned u0 = (unsigned)f2bf(a0) | ((unsigned)f2bf(b0) << 16);
      unsigned u1 = (unsigned)f2bf(a1) | ((unsigned)f2bf(b1) << 16);
      *(unsigned*)(xb + 0 * 128 + (4 * cp)) = u0;                       // p=0, key 0
      *(unsigned*)(xb + 257 * 128 + ((4 * cp) ^ (1 << 3))) = u1;        // p=257, key 1
    }
  }
  __syncthreads();

  f32x4 acc[16];
#pragma unroll
  for (int t = 0; t < 16; ++t) acc[t] = (f32x4){0.f, 0.f, 0.f, 0.f};

  const char* xbc = (const char*)xs;
#pragma unroll
  for (int s = 0; s < 6; ++s) {
    const int kk = s >> 1;
    const int cbyte = 64 * (s & 1) + 16 * g;
#pragma unroll
    for (int nt = 0; nt < 16; ++nt) {
      const int p = 16 * nt + c16 + kk;
      const int sw = (p & 15) << 3;
      union { bf16x8 v; ull d[2]; } A;
      A.d[0] = *(const ull*)(xbc + p * 128 + (cbyte ^ sw));
      A.d[1] = *(const ull*)(xbc + p * 128 + ((cbyte + 8) ^ sw));
      acc[nt] = __builtin_amdgcn_mfma_f32_16x16x32_bf16(A.v, wf[s], acc[nt], 0, 0, 0);
    }
  }

  // epilogue (round-3 proven): co = 16w + c16; pos = l0 + nt*16 + 4g + reg
  const int co = 16 * w + c16;
  const float be = beff[co], se = seff[co];
  float* orow = out + ((size_t)(n * 64 + co)) * 8192 + l0 + 4 * g;
#pragma unroll
  for (int nt = 0; nt < 16; ++nt) {
    float4 ov;
    ov.x = se * (acc[nt][0] + be);
    ov.y = se * (acc[nt][1] + be);
    ov.z = se * (acc[nt][2] + be);
    ov.w = se * (acc[nt][3] + be);
    *(float4*)(orow + nt * 16) = ov;
  }
}

extern "C" void kernel_launch(void* const* d_in, const int* in_sizes, int n_in,
                              void* d_out, int out_size, void* d_ws, size_t ws_size,
                              hipStream_t stream) {
  const float* x = (const float*)d_in[0];
  const float* conv_weight = (const float*)d_in[1];
  const float* bias = (const float*)d_in[2];
  const float* grads = (const float*)d_in[3];
  const float* q_ema = (const float*)d_in[4];
  const float* ctrl_w = (const float*)d_in[5];
  const float* ctrl_b = (const float*)d_in[6];
  const float* gp_w = (const float*)d_in[7];
  const float* gp_b = (const float*)d_in[8];
  const float* gt_w = (const float*)d_in[9];
  const float* gt_b = (const float*)d_in[10];
  const float* ln_g = (const float*)d_in[11];
  const float* ln_b = (const float*)d_in[12];
  const float* ccin_w = (const float*)d_in[13];
  const float* ccin_b = (const float*)d_in[14];
  const float* ck_w = (const float*)d_in[15];
  const float* ck_b = (const float*)d_in[16];
  const float* cb_w = (const float*)d_in[17];
  const float* cb_b = (const float*)d_in[18];
  const float* cf_w = (const float*)d_in[19];
  const float* cf_b = (const float*)d_in[20];
  const float* tau_w = (const float*)d_in[21];
  const float* tau_b = (const float*)d_in[22];
  const float* mem_W = (const float*)d_in[23];
  const float* temp_logit = (const float*)d_in[24];

  float* ws = (float*)d_ws;

  hipLaunchKernelGGL(kCtl, dim3(4), dim3(1024), 0, stream,
                     grads, ctrl_w, ctrl_b, gp_w, gp_b, gt_w, gt_b, ln_g, ln_b,
                     ccin_w, ccin_b, ck_w, ck_b, cb_w, cb_b, cf_w, cf_b,
                     tau_w, tau_b, q_ema, mem_W, temp_logit, conv_weight, bias, ws);
  hipLaunchKernelGGL(k3_s, dim3(32, 64), dim3(256), 0, stream,
                     x, (const unsigned short*)(ws + WS_WFRAG), ws + WS_BEFF, ws + WS_SEFF,
                     (float*)d_out);
}

// Round 7
// 100.805 us; speedup vs baseline: 2.0378x; 1.0170x over previous
//
#include <hip/hip_runtime.h>
#include <math.h>

typedef __attribute__((ext_vector_type(8))) short bf16x8;
typedef __attribute__((ext_vector_type(4))) float f32x4;
typedef unsigned long long ull;

__device__ __forceinline__ float sigmoidf_(float x) { return 1.f / (1.f + expf(-x)); }

__device__ __forceinline__ unsigned short f2bf(float f) {
  unsigned int u = __float_as_uint(f);
  u += 0x7fffu + ((u >> 16) & 1u);   // round-to-nearest-even
  return (unsigned short)(u >> 16);
}

// ws layout (float offsets)
#define WS_BEFF  0       // 64
#define WS_SEFF  64      // 64
#define WS_WFRAG 128     // 12288 ushort = 6144 floats

// ================= kCtl: full controller, one block per group (4 x 1024) =================
__global__ __launch_bounds__(1024) void kCtl(
    const float* __restrict__ grads, const float* __restrict__ ctrl_w, const float* __restrict__ ctrl_b,
    const float* __restrict__ gp_w, const float* __restrict__ gp_b,
    const float* __restrict__ gt_w, const float* __restrict__ gt_b,
    const float* __restrict__ ln_g, const float* __restrict__ ln_b,
    const float* __restrict__ ccin_w, const float* __restrict__ ccin_b,
    const float* __restrict__ ck_w, const float* __restrict__ ck_b,
    const float* __restrict__ cb_w, const float* __restrict__ cb_b,
    const float* __restrict__ cf_w, const float* __restrict__ cf_b,
    const float* __restrict__ tau_w, const float* __restrict__ tau_b,
    const float* __restrict__ q_ema, const float* __restrict__ mem_W,
    const float* __restrict__ temp_logit,
    const float* __restrict__ conv_weight, const float* __restrict__ bias,
    float* __restrict__ ws) {
  __shared__ float rawA[8514];
  __shared__ float sh_h[64 * 65];
  __shared__ float gnp[64 * 17];
  __shared__ float taup[64];
  __shared__ float sh_qg[4416];      // grouped [g][1104]
  __shared__ float part[16][32];
  __shared__ float sv[3];
  __shared__ int sidx[3];
  __shared__ float qc1[16][64];
  __shared__ float qk1[16][3];
  __shared__ float sh_tau;
  const int tid = threadIdx.x;
  const int g = blockIdx.x;
  const int j = tid & 63;
  const int wv = tid >> 6;           // 0..15
  const int i0 = wv * 4;
  const int i0u = __builtin_amdgcn_readfirstlane(i0);

  // ---- h = silu(g @ ctrl_w.T + ctrl_b), K=192 in two halves ----
  float acc[4] = {0.f, 0.f, 0.f, 0.f};
  for (int hh = 0; hh < 2; ++hh) {
    const int d0 = hh * 96;
    for (int t = tid; t < 6144; t += 1024) {
      int jj = t / 96, dl = t - jj * 96;
      rawA[dl * 66 + jj] = ctrl_w[jj * 192 + d0 + dl];
    }
    __syncthreads();
    const float* g0 = grads + i0u * 192 + d0;
#pragma unroll 8
    for (int dl = 0; dl < 96; ++dl) {
      float wvv = rawA[dl * 66 + j];
      acc[0] += wvv * g0[dl];
      acc[1] += wvv * g0[192 + dl];
      acc[2] += wvv * g0[384 + dl];
      acc[3] += wvv * g0[576 + dl];
    }
    __syncthreads();
  }
  {
    float cb_ = ctrl_b[j];
#pragma unroll
    for (int ii = 0; ii < 4; ++ii) {
      float s = acc[ii] + cb_;
      sh_h[(i0 + ii) * 65 + j] = s * sigmoidf_(s);
    }
  }
  // ---- gn partials ----
  {
    int gi = tid >> 4, seg = tid & 15;
    const float* gr = grads + gi * 192 + seg * 12;
    float ss = 0.f;
#pragma unroll
    for (int m = 0; m < 12; ++m) { float v = gr[m]; ss += v * v; }
    gnp[gi * 17 + seg] = ss;
  }
  __syncthreads();
  if (tid < 64) {
    float s = 0.f;
#pragma unroll
    for (int seg = 0; seg < 16; ++seg) s += gnp[tid * 17 + seg];
    gnp[tid * 17 + 16] = sqrtf(s);
  }
  for (int t = tid; t < 4096; t += 1024) rawA[(t & 63) * 66 + (t >> 6)] = gt_w[t];
  for (int t = tid; t < 4160; t += 1024) {
    int jj = t / 65, dd = t - jj * 65;
    rawA[4224 + dd * 66 + jj] = gp_w[t];
  }
  __syncthreads();

  // ---- gates -> hm ----
  float hm[4];
  {
    float zacc[4] = {0.f, 0.f, 0.f, 0.f}, tacc[4] = {0.f, 0.f, 0.f, 0.f};
#pragma unroll 4
    for (int d = 0; d < 64; ++d) {
      float gtv = rawA[d * 66 + j];
      float gpv = rawA[4224 + d * 66 + j];
#pragma unroll
      for (int ii = 0; ii < 4; ++ii) {
        float hv = sh_h[(i0 + ii) * 65 + d];
        tacc[ii] += hv * gtv;
        zacc[ii] += hv * gpv;
      }
    }
    float gplast = rawA[4224 + 64 * 66 + j];
    float zb = gp_b[j], tb = gt_b[j];
#pragma unroll
    for (int ii = 0; ii < 4; ++ii) {
      float gn_ = gnp[(i0 + ii) * 17 + 16];
      float zs = zacc[ii] + gn_ * gplast + zb;
      float ts = tacc[ii] + tb;
      float z = sigmoidf_(zs);
      float ht = ts * sigmoidf_(ts);
      hm[ii] = (1.f - z) * sh_h[(i0 + ii) * 65 + j] + z * ht;
    }
  }
  __syncthreads();
#pragma unroll
  for (int ii = 0; ii < 4; ++ii) sh_h[(i0 + ii) * 65 + j] = hm[ii];
  __syncthreads();

  // ---- LN + stage ccinT/ext ----
  {
    float lg = ln_g[j], lb = ln_b[j];
#pragma unroll
    for (int ii = 0; ii < 4; ++ii) {
      float x = sh_h[(i0 + ii) * 65 + j];
      float s = x;
#pragma unroll
      for (int off = 32; off; off >>= 1) s += __shfl_xor(s, off);
      float mu = s * (1.f / 64.f);
      float dv = x - mu;
      float v2 = dv * dv;
#pragma unroll
      for (int off = 32; off; off >>= 1) v2 += __shfl_xor(v2, off);
      float invs = 1.f / sqrtf(v2 * (1.f / 64.f) + 1e-5f);
      sh_h[(i0 + ii) * 65 + j] = lg * dv * invs + lb;
    }
  }
  for (int t = tid; t < 4096; t += 1024) rawA[(t & 63) * 66 + (t >> 6)] = ccin_w[t];
  if (tid < 384) {
    int c = tid >> 6, d = tid & 63;
    float v = (c < 3) ? ck_w[c * 64 + d] : (c == 3) ? cb_w[d] : (c == 4) ? cf_w[d] : tau_w[d];
    rawA[4224 + c * 64 + d] = v;
  }
  __syncthreads();

  // ---- w_cin head (all rows) ----
  {
    float cb_ = ccin_b[j];
    float s4[4] = {0.f, 0.f, 0.f, 0.f};
#pragma unroll 4
    for (int d = 0; d < 64; ++d) {
      float cv = rawA[d * 66 + j];
#pragma unroll
      for (int ii = 0; ii < 4; ++ii) s4[ii] += sh_h[(i0 + ii) * 65 + d] * cv;
    }
#pragma unroll
    for (int ii = 0; ii < 4; ++ii) {
      int i = i0 + ii;
      float val = 2.f * tanhf(s4[ii] + cb_);
      sh_qg[(i >> 4) * 1104 + (i & 15) * 64 + j] = 0.7f * val + 0.3f * q_ema[i * 64 + j];
    }
  }
  // ---- extras: ck(3), cb, cf, tau ----
  if (wv < 6) {
    int i = j;
    float s = 0.f;
    const float* er = rawA + 4224 + wv * 64;
#pragma unroll 4
    for (int d = 0; d < 64; ++d) s += sh_h[i * 65 + d] * er[d];
    if (wv < 3) {
      float val = 2.f * tanhf(s + ck_b[wv]);
      sh_qg[(i >> 4) * 1104 + 1024 + (i & 15) * 3 + wv] = 0.7f * val + 0.3f * q_ema[4096 + i * 3 + wv];
    } else if (wv == 3) {
      float val = 2.f * tanhf(s + cb_b[0]);
      sh_qg[(i >> 4) * 1104 + 1072 + (i & 15)] = 0.7f * val + 0.3f * q_ema[4288 + i];
    } else if (wv == 4) {
      float val = 2.f * tanhf(s + cf_b[0]);
      sh_qg[(i >> 4) * 1104 + 1088 + (i & 15)] = 0.7f * val + 0.3f * q_ema[4352 + i];
    } else {
      taup[i] = sigmoidf_(s + tau_b[0]);
    }
  }
  __syncthreads();
  if (tid < 64) {
    float t_ = taup[tid];
#pragma unroll
    for (int off = 32; off; off >>= 1) t_ += __shfl_xor(t_, off);
    if (tid == 0) sh_tau = (t_ * (1.f / 64.f)) * 0.5f + 0.5f;
  }
  __syncthreads();

  // ---- attention scores for this group ----
  const float* mwg = mem_W + (size_t)g * 1104 * 32;
  {
    float4 a = {0.f, 0.f, 0.f, 0.f};
    const float* qg = sh_qg + g * 1104;
#pragma unroll
    for (int it = 0; it < 9; ++it) {
      int d = it * 128 + (tid >> 3);
      if (d < 1104) {
        float4 v4 = *(const float4*)(mwg + (size_t)d * 32 + (tid & 7) * 4);
        float qv = qg[d];
        a.x += qv * v4.x; a.y += qv * v4.y; a.z += qv * v4.z; a.w += qv * v4.w;
      }
    }
#pragma unroll
    for (int off = 8; off <= 32; off <<= 1) {
      a.x += __shfl_xor(a.x, off); a.y += __shfl_xor(a.y, off);
      a.z += __shfl_xor(a.z, off); a.w += __shfl_xor(a.w, off);
    }
    if ((tid & 63) < 8) *(float4*)&part[tid >> 6][(tid & 7) * 4] = a;
  }
  __syncthreads();

  // ---- softmax + top3 ----
  if (tid < 32) {
    int m = tid;
    float att = 0.f;
#pragma unroll
    for (int w = 0; w < 16; ++w) att += part[w][m];
    float temp = 0.6f * sigmoidf_(temp_logit[g]) + 0.2f;
    att /= (temp + 1e-8f);
    float mx = att;
#pragma unroll
    for (int off = 16; off; off >>= 1) mx = fmaxf(mx, __shfl_xor(mx, off, 32));
    float e = expf(att - mx);
    float s = e;
#pragma unroll
    for (int off = 16; off; off >>= 1) s += __shfl_xor(s, off, 32);
    float p = e / s;
    for (int t = 0; t < 3; ++t) {
      float bp = p; int bm = m;
#pragma unroll
      for (int off = 16; off; off >>= 1) {
        float op = __shfl_xor(bp, off, 32);
        int om = __shfl_xor(bm, off, 32);
        if (op > bp || (op == bp && om < bm)) { bp = op; bm = om; }
      }
      if (m == 0) { sv[t] = bp; sidx[t] = bm; }
      if (m == bm) p = -1.f;
    }
  }
  __syncthreads();

  // ---- q-final blend for this group's 16 co ----
  {
    const float tau = sh_tau;
    const float v0 = sv[0], v1 = sv[1], v2 = sv[2];
    const int x0 = sidx[0], x1 = sidx[1], x2 = sidx[2];
    const float* qg = sh_qg + g * 1104;
    int cl = wv;           // 0..15
    int co = 16 * g + cl;
    int lane = j;
    {
      int d = cl * 64 + lane;
      float r = v0 * mwg[(size_t)d * 32 + x0] + v1 * mwg[(size_t)d * 32 + x1] + v2 * mwg[(size_t)d * 32 + x2];
      qc1[cl][lane] = 1.f + tau * qg[d] + (1.f - tau) * r;
    }
    if (lane < 3) {
      int d = 1024 + cl * 3 + lane;
      float r = v0 * mwg[(size_t)d * 32 + x0] + v1 * mwg[(size_t)d * 32 + x1] + v2 * mwg[(size_t)d * 32 + x2];
      qk1[cl][lane] = 1.f + tau * qg[d] + (1.f - tau) * r;
    }
    if (lane == 3) {
      int d = 1072 + cl;
      float r = v0 * mwg[(size_t)d * 32 + x0] + v1 * mwg[(size_t)d * 32 + x1] + v2 * mwg[(size_t)d * 32 + x2];
      float qb = tau * qg[d] + (1.f - tau) * r;
      ws[WS_BEFF + co] = bias[co] * (1.f + qb);
    }
    if (lane == 4) {
      int d = 1088 + cl;
      float r = v0 * mwg[(size_t)d * 32 + x0] + v1 * mwg[(size_t)d * 32 + x1] + v2 * mwg[(size_t)d * 32 + x2];
      ws[WS_SEFF + co] = 1.f + tau * qg[d] + (1.f - tau) * r;
    }
  }
  __syncthreads();

  // ---- pack wfrag for this group's 16 co (3072 entries) ----
  unsigned short* wfrag = (unsigned short*)(ws + WS_WFRAG);
  for (int idx = tid; idx < 3072; idx += 1024) {
    int cl = idx / 192, rem = idx - cl * 192;
    int kk = rem >> 6, ci = rem & 63;
    int co = 16 * g + cl;
    float val = conv_weight[(co * 64 + ci) * 3 + kk] * qc1[cl][ci] * qk1[cl][kk];
    int e = kk * 64 + ci;
    int s = e >> 5, hi = (e >> 3) & 3, jj = e & 7;
    wfrag[s * 2048 + g * 512 + (16 * hi + cl) * 8 + jj] = f2bf(val);
  }
}

// ================= k3_v7: direct MFMA conv, 128-pos tiles, b128 fragment reads ============
// grid (64 l-tiles of 128, 64 batches), 256 threads = 4 waves.
// LDS row p (128 B = 32 u32 ci-pairs) ↔ global pos l0 + p - 1, p = 0..129.
// swizzle: byte ^= (p&7)<<4 (16-B granule) -> each A fragment is ONE aligned b128.
__global__ __launch_bounds__(256, 5) void k3_v7(
    const float* __restrict__ x, const unsigned short* __restrict__ wfrag,
    const float* __restrict__ beff, const float* __restrict__ seff,
    float* __restrict__ out) {
  __shared__ unsigned short xs[130 * 64];   // 16640 B
  const int tid = threadIdx.x;
  const int w = tid >> 6, l = tid & 63;
  const int g = l >> 4, c16 = l & 15;
  const int n = blockIdx.y;
  const int l0 = blockIdx.x * 128;

  // B fragments
  bf16x8 wf[6];
#pragma unroll
  for (int s = 0; s < 6; ++s)
    wf[s] = *(const bf16x8*)(wfrag + s * 2048 + w * 512 + l * 8);

  // staging: cp = ci-pair owned by this lane; rows 2cp, 2cp+1 pair-packed as u32
  {
    const int cp = 8 * w + (l >> 3);
    const float* r0 = x + ((size_t)(n * 64 + 2 * cp)) * 8192 + l0;
    const float* r1 = r0 + 8192;
    char* xb = (char*)xs;
#pragma unroll
    for (int t = 0; t < 4; ++t) {
      int p0 = 4 * ((l & 7) + 8 * t);
      float4 va = *(const float4*)(r0 + p0);
      float4 vb = *(const float4*)(r1 + p0);
      float av[4] = {va.x, va.y, va.z, va.w};
      float bv[4] = {vb.x, vb.y, vb.z, vb.w};
#pragma unroll
      for (int i = 0; i < 4; ++i) {
        int p = p0 + i + 1;
        unsigned u = (unsigned)f2bf(av[i]) | ((unsigned)f2bf(bv[i]) << 16);
        *(unsigned*)(xb + p * 128 + ((4 * cp) ^ ((p & 7) << 4))) = u;
      }
    }
    // halo rows 0 (pos l0-1) and 129 (pos l0+128), lanes with (l&7)==0
    if ((l & 7) == 0) {
      float a0 = 0.f, b0 = 0.f, a1 = 0.f, b1 = 0.f;
      if (l0 > 0) {
        float4 va = *(const float4*)(r0 - 4);
        float4 vb = *(const float4*)(r1 - 4);
        a0 = va.w; b0 = vb.w;
      }
      if (l0 + 128 < 8192) {
        float4 va = *(const float4*)(r0 + 128);
        float4 vb = *(const float4*)(r1 + 128);
        a1 = va.x; b1 = vb.x;
      }
      unsigned u0 = (unsigned)f2bf(a0) | ((unsigned)f2bf(b0) << 16);
      unsigned u1 = (unsigned)f2bf(a1) | ((unsigned)f2bf(b1) << 16);
      *(unsigned*)(xb + 0 * 128 + (4 * cp)) = u0;                 // p=0: key 0
      *(unsigned*)(xb + 129 * 128 + ((4 * cp) ^ 16)) = u1;        // p=129: key (1<<4)
    }
  }
  __syncthreads();

  f32x4 acc[8];
#pragma unroll
  for (int t = 0; t < 8; ++t) acc[t] = (f32x4){0.f, 0.f, 0.f, 0.f};

  const char* xbc = (const char*)xs;
#pragma unroll
  for (int s = 0; s < 6; ++s) {
    const int kk = s >> 1;
    const int C = 4 * (s & 1) + g;      // 16-B chunk index of this lane's fragment
#pragma unroll
    for (int nt = 0; nt < 8; ++nt) {
      const int p = 16 * nt + c16 + kk;
      bf16x8 A = *(const bf16x8*)(xbc + p * 128 + ((C ^ (p & 7)) << 4));
      acc[nt] = __builtin_amdgcn_mfma_f32_16x16x32_bf16(A, wf[s], acc[nt], 0, 0, 0);
    }
  }

  // epilogue: co = 16w + c16; pos = l0 + nt*16 + 4g + reg
  const int co = 16 * w + c16;
  const float be = beff[co], se = seff[co];
  float* orow = out + ((size_t)(n * 64 + co)) * 8192 + l0 + 4 * g;
#pragma unroll
  for (int nt = 0; nt < 8; ++nt) {
    float4 ov;
    ov.x = se * (acc[nt][0] + be);
    ov.y = se * (acc[nt][1] + be);
    ov.z = se * (acc[nt][2] + be);
    ov.w = se * (acc[nt][3] + be);
    *(float4*)(orow + nt * 16) = ov;
  }
}

extern "C" void kernel_launch(void* const* d_in, const int* in_sizes, int n_in,
                              void* d_out, int out_size, void* d_ws, size_t ws_size,
                              hipStream_t stream) {
  const float* x = (const float*)d_in[0];
  const float* conv_weight = (const float*)d_in[1];
  const float* bias = (const float*)d_in[2];
  const float* grads = (const float*)d_in[3];
  const float* q_ema = (const float*)d_in[4];
  const float* ctrl_w = (const float*)d_in[5];
  const float* ctrl_b = (const float*)d_in[6];
  const float* gp_w = (const float*)d_in[7];
  const float* gp_b = (const float*)d_in[8];
  const float* gt_w = (const float*)d_in[9];
  const float* gt_b = (const float*)d_in[10];
  const float* ln_g = (const float*)d_in[11];
  const float* ln_b = (const float*)d_in[12];
  const float* ccin_w = (const float*)d_in[13];
  const float* ccin_b = (const float*)d_in[14];
  const float* ck_w = (const float*)d_in[15];
  const float* ck_b = (const float*)d_in[16];
  const float* cb_w = (const float*)d_in[17];
  const float* cb_b = (const float*)d_in[18];
  const float* cf_w = (const float*)d_in[19];
  const float* cf_b = (const float*)d_in[20];
  const float* tau_w = (const float*)d_in[21];
  const float* tau_b = (const float*)d_in[22];
  const float* mem_W = (const float*)d_in[23];
  const float* temp_logit = (const float*)d_in[24];

  float* ws = (float*)d_ws;

  hipLaunchKernelGGL(kCtl, dim3(4), dim3(1024), 0, stream,
                     grads, ctrl_w, ctrl_b, gp_w, gp_b, gt_w, gt_b, ln_g, ln_b,
                     ccin_w, ccin_b, ck_w, ck_b, cb_w, cb_b, cf_w, cf_b,
                     tau_w, tau_b, q_ema, mem_W, temp_logit, conv_weight, bias, ws);
  hipLaunchKernelGGL(k3_v7, dim3(64, 64), dim3(256), 0, stream,
                     x, (const unsigned short*)(ws + WS_WFRAG), ws + WS_BEFF, ws + WS_SEFF,
                     (float*)d_out);
}